// Round 15
// baseline (331.589 us; speedup 1.0000x reference)
//
#include <hip/hip_runtime.h>

#define NNODES 50000
#define NEDGES 600000
#define HID 128
#define NLAYERS 4
#define NOUT 8
#define BN_EPS 1e-5f
#define NBLK 196    // ceil(NNODES/256)
#define NPBLK 3125  // NNODES/16 — 16-row MFMA blocks (2 waves, N-split)
#define NCOPY 8     // histogram copies (XCD-affine via blockIdx%8)
#define IDXCAP 1024 // staged edge-index capacity per gather block

typedef short short8 __attribute__((ext_vector_type(8)));
typedef float f32x4 __attribute__((ext_vector_type(4)));

__device__ inline unsigned short f2bf(float f) {
  unsigned u = __float_as_uint(f);
  unsigned r = ((u >> 16) & 1u) + 0x7fffu;
  return (unsigned short)((u + r) >> 16);
}
__device__ inline float bflo(unsigned w) { return __uint_as_float(w << 16); }
__device__ inline float bfhi(unsigned w) { return __uint_as_float(w & 0xffff0000u); }

// ---------------- utility kernels ----------------

// Detect whether edge_index arrived as int64 (odd int32 words all zero) or int32.
__global__ void detect64_k(const int* __restrict__ ei, int* __restrict__ flag) {
  __shared__ int anynz;
  if (threadIdx.x == 0) anynz = 0;
  __syncthreads();
  int acc = 0;
  for (int i = threadIdx.x; i < 4096; i += 256) {
    int p = i * 146;
    acc |= ei[2 * p + 1];
  }
  if (acc != 0) anynz = 1;
  __syncthreads();
  if (threadIdx.x == 0) *flag = (anynz == 0) ? 1 : 0;  // 1 => int64 layout
}

// fp32 -> bf16 convert (for the input x gather table)
__global__ void cvt_bf_k(const float* __restrict__ src, unsigned short* __restrict__ dst,
                         int n4) {
  int i = blockIdx.x * 256 + threadIdx.x;
  if (i >= n4) return;
  float4 v = ((const float4*)src)[i];
  ushort4 o;
  o.x = f2bf(v.x);
  o.y = f2bf(v.y);
  o.z = f2bf(v.z);
  o.w = f2bf(v.w);
  ((ushort4*)dst)[i] = o;
}

// ---------------- CSR build (8-copy histogram, rank capture, no-atomic fill) --------

__global__ void zero_degc_k(int* __restrict__ degC) {
  int i = blockIdx.x * 256 + threadIdx.x;
  if (i < NCOPY * NNODES) degC[i] = 0;
}

__global__ void hist_rank_k(const int* __restrict__ ei, const int* __restrict__ flag,
                            int* __restrict__ degC, int* __restrict__ rank) {
  int e = blockIdx.x * 256 + threadIdx.x;
  if (e >= NEDGES) return;
  int d = (*flag) ? ei[2 * NEDGES + 2 * e] : ei[NEDGES + e];
  int c = blockIdx.x & (NCOPY - 1);
  rank[e] = atomicAdd(&degC[c * NNODES + d], 1);
}

__global__ void coff_k(int* __restrict__ degC, int* __restrict__ deg) {
  int d = blockIdx.x * 256 + threadIdx.x;
  if (d >= NNODES) return;
  int run = 0;
#pragma unroll
  for (int c = 0; c < NCOPY; ++c) {
    int t = degC[c * NNODES + d];
    degC[c * NNODES + d] = run;
    run += t;
  }
  deg[d] = run;
}

__global__ void blocksum_k(const int* __restrict__ deg, int* __restrict__ bsum) {
  int t = threadIdx.x;
  int i = blockIdx.x * 256 + t;
  __shared__ int sh[256];
  sh[t] = (i < NNODES) ? deg[i] : 0;
  __syncthreads();
  for (int s = 128; s > 0; s >>= 1) {
    if (t < s) sh[t] += sh[t + s];
    __syncthreads();
  }
  if (t == 0) bsum[blockIdx.x] = sh[0];
}

__global__ void scanb_k(const int* __restrict__ bsum, int* __restrict__ boff) {
  __shared__ int sh[256];
  int t = threadIdx.x;
  sh[t] = (t < NBLK) ? bsum[t] : 0;
  __syncthreads();
  for (int d = 1; d < 256; d <<= 1) {
    int v = (t >= d) ? sh[t - d] : 0;
    __syncthreads();
    sh[t] += v;
    __syncthreads();
  }
  if (t < NBLK) boff[t] = (t == 0) ? 0 : sh[t - 1];
}

__global__ void writeoff_k(const int* __restrict__ deg, const int* __restrict__ boff,
                           int* __restrict__ off) {
  int t = threadIdx.x;
  int i = blockIdx.x * 256 + t;
  __shared__ int sh[256];
  int v = (i < NNODES) ? deg[i] : 0;
  sh[t] = v;
  __syncthreads();
  for (int d = 1; d < 256; d <<= 1) {
    int u = (t >= d) ? sh[t - d] : 0;
    __syncthreads();
    sh[t] += u;
    __syncthreads();
  }
  int excl = boff[blockIdx.x] + sh[t] - v;
  if (i < NNODES) off[i] = excl;
  if (i == NNODES - 1) off[NNODES] = excl + v;
}

__global__ void fill2_k(const int* __restrict__ ei, const int* __restrict__ flag,
                        const int* __restrict__ off, const int* __restrict__ degC,
                        const int* __restrict__ rank, int* __restrict__ srcs) {
  int e = blockIdx.x * 256 + threadIdx.x;
  if (e >= NEDGES) return;
  int s, d;
  if (*flag) {
    s = ei[2 * e];
    d = ei[2 * NEDGES + 2 * e];
  } else {
    s = ei[e];
    d = ei[NEDGES + e];
  }
  int c = blockIdx.x & (NCOPY - 1);
  srcs[off[d] + degC[c * NNODES + d] + rank[e]] = s;
}

// ---------------- fused gather-aggregate + optional BN affine ----------------
// 8 nodes/block, CSR metadata LDS-staged. If AFFINE: out = alpha*S + (1+deg)*beta
// (folds the previous layer's BatchNorm into the aggregation — bn_norm kernel deleted).
template <bool AFFINE>
__global__ void gather_agg_k(const unsigned short* __restrict__ X,
                             const int* __restrict__ off, const int* __restrict__ srcs,
                             const float* __restrict__ ab, unsigned short* __restrict__ T) {
  __shared__ int sOff[9];
  __shared__ int sIdx[IDXCAP];
  int tid = threadIdx.x;
  int nb = blockIdx.x * 8;
  if (tid < 9) sOff[tid] = off[nb + tid];
  __syncthreads();
  int base = sOff[0];
  int total = sOff[8] - base;
  int stage = total > IDXCAP ? IDXCAP : total;
  for (int t = tid; t < stage; t += 256) sIdx[t] = srcs[base + t];
  __syncthreads();

  int g = tid >> 5, lane = tid & 31;
  int node = nb + g;
  int a = sOff[g] - base, bnd = sOff[g + 1] - base;
  const uint2* Xv = (const uint2*)X;
  uint2 w = Xv[(size_t)node * 32 + lane];
  float a0 = bflo(w.x), a1 = bfhi(w.x), a2 = bflo(w.y), a3 = bfhi(w.y);

  if (total <= IDXCAP) {
    int e = a;
#pragma unroll
    for (; e + 4 <= bnd; e += 4) {
      int s0 = sIdx[e], s1 = sIdx[e + 1], s2 = sIdx[e + 2], s3 = sIdx[e + 3];
      uint2 v0 = Xv[(size_t)s0 * 32 + lane];
      uint2 v1 = Xv[(size_t)s1 * 32 + lane];
      uint2 v2 = Xv[(size_t)s2 * 32 + lane];
      uint2 v3 = Xv[(size_t)s3 * 32 + lane];
      a0 += bflo(v0.x); a1 += bfhi(v0.x); a2 += bflo(v0.y); a3 += bfhi(v0.y);
      a0 += bflo(v1.x); a1 += bfhi(v1.x); a2 += bflo(v1.y); a3 += bfhi(v1.y);
      a0 += bflo(v2.x); a1 += bfhi(v2.x); a2 += bflo(v2.y); a3 += bfhi(v2.y);
      a0 += bflo(v3.x); a1 += bfhi(v3.x); a2 += bflo(v3.y); a3 += bfhi(v3.y);
    }
    for (; e < bnd; ++e) {
      int s = sIdx[e];
      uint2 v = Xv[(size_t)s * 32 + lane];
      a0 += bflo(v.x); a1 += bfhi(v.x); a2 += bflo(v.y); a3 += bfhi(v.y);
    }
  } else {
    for (int e = a; e < bnd; ++e) {
      int s = srcs[base + e];
      uint2 v = Xv[(size_t)s * 32 + lane];
      a0 += bflo(v.x); a1 += bfhi(v.x); a2 += bflo(v.y); a3 += bfhi(v.y);
    }
  }

  if (AFFINE) {
    float4 al = *(const float4*)(ab + lane * 4);
    float4 be = *(const float4*)(ab + 128 + lane * 4);
    float dp1 = (float)(bnd - a + 1);  // 1 + deg (self term)
    a0 = al.x * a0 + dp1 * be.x;
    a1 = al.y * a1 + dp1 * be.y;
    a2 = al.z * a2 + dp1 * be.z;
    a3 = al.w * a3 + dp1 * be.w;
  }

  uint2 o;
  o.x = (unsigned)f2bf(a0) | ((unsigned)f2bf(a1) << 16);
  o.y = (unsigned)f2bf(a2) | ((unsigned)f2bf(a3) << 16);
  ((uint2*)T)[(size_t)node * 32 + lane] = o;
}

// ---------------- weight pre-pack into MFMA B-fragment layout (W1, W2 only) --------
__global__ void packW_k(const float* __restrict__ W1, const float* __restrict__ W2,
                        unsigned short* __restrict__ P) {
  int t = blockIdx.x * 256 + threadIdx.x;
  if (t >= 32 * 512) return;
  int gk = t >> 9;
  int nt = (t >> 6) & 7;
  int lane = t & 63;
  const float* src;
  int kbase;
  if (gk < 16) {
    src = W1 + (gk >> 2) * 16384;
    kbase = (gk & 3) * 32;
  } else {
    src = W2 + ((gk - 16) >> 2) * 16384;
    kbase = ((gk - 16) & 3) * 32;
  }
  int n = nt * 16 + (lane & 15);
  int k0 = kbase + (lane >> 4) * 8;
  unsigned short* dst = P + (size_t)t * 8;
#pragma unroll
  for (int j = 0; j < 8; ++j) dst[j] = f2bf(src[(size_t)(k0 + j) * HID + n]);
}

// ---------------- JK weight pack with alpha fold: W'[K,n] = alpha_K * L1[K,n] --------
__global__ void packjk_k(const float* __restrict__ L1, const float* __restrict__ ab,
                         unsigned short* __restrict__ Pjk) {
  int t = blockIdx.x * 256 + threadIdx.x;
  if (t >= 16 * 512) return;
  int gk = t >> 9;
  int nt = (t >> 6) & 7;
  int lane = t & 63;
  int n = nt * 16 + (lane & 15);
  int k0 = gk * 32 + (lane >> 4) * 8;
  unsigned short* dst = Pjk + (size_t)t * 8;
#pragma unroll
  for (int j = 0; j < 8; ++j) {
    int K = k0 + j;
    float al = ab[(K >> 7) * 256 + (K & 127)];
    dst[j] = f2bf(al * L1[(size_t)K * HID + n]);
  }
}

// ---------------- JK bias with beta fold: b'[n] = l1b[n] + sum_K beta_K * L1[K,n] ----
__global__ void biasjk_k(const float* __restrict__ L1, const float* __restrict__ ab,
                         const float* __restrict__ l1b, float* __restrict__ bjk) {
  int n = threadIdx.x;  // 128
  float acc = l1b[n];
  for (int K = 0; K < 4 * HID; ++K) {
    float be = ab[(K >> 7) * 256 + 128 + (K & 127)];
    acc += be * L1[(size_t)K * HID + n];
  }
  bjk[n] = acc;
}

// ---------------- fused MLP: Hq = bf16(relu(relu(A@W1+b1)@W2+b2)); stats -> pstats ----
__global__ __launch_bounds__(128) void mlp_k(const unsigned short* __restrict__ A,
                                             const unsigned short* __restrict__ P1,
                                             const float* __restrict__ bias1,
                                             const unsigned short* __restrict__ P2,
                                             const float* __restrict__ bias2,
                                             unsigned short* __restrict__ Hq, int M,
                                             float* __restrict__ pstats) {
  __shared__ unsigned short sA[16 * 136];
  int tid = threadIdx.x;
  int lane = tid & 63, w = tid >> 6;
  int rb = blockIdx.x * 16;
  int r = rb + (lane & 15);
  int hi = lane >> 4, c = lane & 15;
  int koff = hi * 8;
  int ntb = w * 4;

  short8 a_[4];
  const unsigned short* Ar = A + (size_t)r * HID + koff;
#pragma unroll
  for (int ks = 0; ks < 4; ++ks) a_[ks] = *(const short8*)(Ar + ks * 32);

  const short8* Bp1 = (const short8*)P1;
  f32x4 acc[4];
#pragma unroll
  for (int nt = 0; nt < 4; ++nt) acc[nt] = (f32x4){0.f, 0.f, 0.f, 0.f};
  short8 bcur[4], bnxt[4];
#pragma unroll
  for (int nt = 0; nt < 4; ++nt) bcur[nt] = Bp1[(ntb + nt) * 64 + lane];
#pragma unroll
  for (int ks = 0; ks < 4; ++ks) {
    if (ks < 3) {
#pragma unroll
      for (int nt = 0; nt < 4; ++nt) bnxt[nt] = Bp1[(ks + 1) * 512 + (ntb + nt) * 64 + lane];
    }
#pragma unroll
    for (int nt = 0; nt < 4; ++nt)
      acc[nt] = __builtin_amdgcn_mfma_f32_16x16x32_bf16(a_[ks], bcur[nt], acc[nt], 0, 0, 0);
    if (ks < 3) {
#pragma unroll
      for (int nt = 0; nt < 4; ++nt) bcur[nt] = bnxt[nt];
    }
  }
#pragma unroll
  for (int nt = 0; nt < 4; ++nt) {
    int col = (ntb + nt) * 16 + c;
    float b = bias1[col];
#pragma unroll
    for (int rr = 0; rr < 4; ++rr) {
      float v = fmaxf(acc[nt][rr] + b, 0.f);
      sA[(hi * 4 + rr) * 136 + col] = f2bf(v);
    }
  }
  __syncthreads();

#pragma unroll
  for (int nt = 0; nt < 4; ++nt) acc[nt] = (f32x4){0.f, 0.f, 0.f, 0.f};
  const short8* Bp2 = (const short8*)P2;
#pragma unroll
  for (int nt = 0; nt < 4; ++nt) bcur[nt] = Bp2[(ntb + nt) * 64 + lane];
#pragma unroll
  for (int ks = 0; ks < 4; ++ks) {
    short8 af = *(const short8*)&sA[c * 136 + ks * 32 + koff];
    if (ks < 3) {
#pragma unroll
      for (int nt = 0; nt < 4; ++nt) bnxt[nt] = Bp2[(ks + 1) * 512 + (ntb + nt) * 64 + lane];
    }
#pragma unroll
    for (int nt = 0; nt < 4; ++nt)
      acc[nt] = __builtin_amdgcn_mfma_f32_16x16x32_bf16(af, bcur[nt], acc[nt], 0, 0, 0);
    if (ks < 3) {
#pragma unroll
      for (int nt = 0; nt < 4; ++nt) bcur[nt] = bnxt[nt];
    }
  }
  // epilogue 2: relu + bf16 write + BN stat partials (stats from fp32 values)
  float* dst = pstats + (size_t)blockIdx.x * 256;
#pragma unroll
  for (int nt = 0; nt < 4; ++nt) {
    int col = (ntb + nt) * 16 + c;
    float b = bias2[col];
    float s = 0.f, q = 0.f;
#pragma unroll
    for (int rr = 0; rr < 4; ++rr) {
      int row = rb + hi * 4 + rr;
      float v = fmaxf(acc[nt][rr] + b, 0.f);
      Hq[(size_t)row * HID + col] = f2bf(v);
      s += v;
      q += v * v;
    }
    s += __shfl_xor(s, 16, 64);
    q += __shfl_xor(q, 16, 64);
    s += __shfl_xor(s, 32, 64);
    q += __shfl_xor(q, 32, 64);
    if (hi == 0) {
      dst[col] = s;
      dst[128 + col] = q;
    }
  }
}

// ---------------- stats reduce + BN affine coefficients: ab = {alpha[128], beta[128]} --
__global__ void reduce_ab_k(const float* __restrict__ pstats, const float* __restrict__ gamma,
                            const float* __restrict__ beta, float* __restrict__ ab) {
  __shared__ float sh[256], sh2[256];
  int j = blockIdx.x;  // channel
  int t = threadIdx.x;
  float s = 0.f, q = 0.f;
  for (int b = t; b < NPBLK; b += 256) {
    s += pstats[(size_t)b * 256 + j];
    q += pstats[(size_t)b * 256 + 128 + j];
  }
  sh[t] = s;
  sh2[t] = q;
  __syncthreads();
  for (int st = 128; st > 0; st >>= 1) {
    if (t < st) {
      sh[t] += sh[t + st];
      sh2[t] += sh2[t + st];
    }
    __syncthreads();
  }
  if (t == 0) {
    const float invN = 1.0f / (float)NNODES;
    float m = sh[0] * invN;
    float var = sh2[0] * invN - m * m;
    float al = gamma[j] * rsqrtf(var + BN_EPS);
    ab[j] = al;
    ab[128 + j] = beta[j] - m * al;
  }
}

// ---------------- MFMA JK GEMM: t2 = relu(concat(hq) @ W' + b'), fp32 out ----
__global__ __launch_bounds__(128) void mjkgemm_k(const unsigned short* __restrict__ H0,
                                                 const unsigned short* __restrict__ H1,
                                                 const unsigned short* __restrict__ H2,
                                                 const unsigned short* __restrict__ H3,
                                                 const unsigned short* __restrict__ P,
                                                 const float* __restrict__ bias,
                                                 float* __restrict__ C, int M) {
  int tid = threadIdx.x;
  int lane = tid & 63, w = tid >> 6;
  int rb = blockIdx.x * 16;
  int r = rb + (lane & 15);
  int koff = (lane >> 4) * 8;
  int ntb = w * 4;
  f32x4 acc[4];
#pragma unroll
  for (int nt = 0; nt < 4; ++nt) acc[nt] = (f32x4){0.f, 0.f, 0.f, 0.f};
  const unsigned short* Hs[4] = {H0, H1, H2, H3};
  short8 bcur[4], bnxt[4];
  for (int l = 0; l < 4; ++l) {
    const short8* Bp = (const short8*)(P + l * 16384);
    short8 a_[4];
    const unsigned short* Ar = Hs[l] + (size_t)r * HID + koff;
#pragma unroll
    for (int ks = 0; ks < 4; ++ks) a_[ks] = *(const short8*)(Ar + ks * 32);
#pragma unroll
    for (int nt = 0; nt < 4; ++nt) bcur[nt] = Bp[(ntb + nt) * 64 + lane];
#pragma unroll
    for (int ks = 0; ks < 4; ++ks) {
      if (ks < 3) {
#pragma unroll
        for (int nt = 0; nt < 4; ++nt) bnxt[nt] = Bp[(ks + 1) * 512 + (ntb + nt) * 64 + lane];
      }
#pragma unroll
      for (int nt = 0; nt < 4; ++nt)
        acc[nt] = __builtin_amdgcn_mfma_f32_16x16x32_bf16(a_[ks], bcur[nt], acc[nt], 0, 0, 0);
      if (ks < 3) {
#pragma unroll
        for (int nt = 0; nt < 4; ++nt) bcur[nt] = bnxt[nt];
      }
    }
  }
  int hi = lane >> 4, c = lane & 15;
#pragma unroll
  for (int nt = 0; nt < 4; ++nt) {
    int col = (ntb + nt) * 16 + c;
    float b = bias[col];
#pragma unroll
    for (int rr = 0; rr < 4; ++rr) {
      int row = rb + hi * 4 + rr;
      float v = fmaxf(acc[nt][rr] + b, 0.f);
      C[(size_t)row * HID + col] = v;
    }
  }
}

// ---------------- head: out[M,8] = t2[M,128] @ W[128,8] + b ----------------
__global__ void head_k(const float* __restrict__ O1, const float* __restrict__ W,
                       const float* __restrict__ b, float* __restrict__ out, int M) {
  __shared__ float sW[HID * NOUT];
  int tid = threadIdx.x;
#pragma unroll
  for (int i = 0; i < 4; ++i) sW[tid + i * 256] = W[tid + i * 256];
  __syncthreads();
  int row = blockIdx.x * 256 + tid;
  if (row >= M) return;
  float acc[NOUT];
#pragma unroll
  for (int j = 0; j < NOUT; ++j) acc[j] = b[j];
  const float* Ar = O1 + (size_t)row * HID;
  for (int k = 0; k < HID; k += 4) {
    float4 a = *(const float4*)(Ar + k);
#pragma unroll
    for (int kk = 0; kk < 4; ++kk) {
      float av = ((const float*)&a)[kk];
#pragma unroll
      for (int j = 0; j < NOUT; ++j) acc[j] += av * sW[(k + kk) * NOUT + j];
    }
  }
#pragma unroll
  for (int j = 0; j < NOUT; ++j) out[(size_t)row * NOUT + j] = acc[j];
}

// ---------------- launch ----------------

extern "C" void kernel_launch(void* const* d_in, const int* in_sizes, int n_in,
                              void* d_out, int out_size, void* d_ws, size_t ws_size,
                              hipStream_t stream) {
  const float* x     = (const float*)d_in[0];
  const int*   ei    = (const int*)d_in[1];
  const float* W1    = (const float*)d_in[2];
  const float* b1    = (const float*)d_in[3];
  const float* W2    = (const float*)d_in[4];
  const float* b2    = (const float*)d_in[5];
  const float* gamma = (const float*)d_in[6];
  const float* beta  = (const float*)d_in[7];
  const float* l1W   = (const float*)d_in[8];
  const float* l1b   = (const float*)d_in[9];
  const float* l2W   = (const float*)d_in[10];
  const float* l2b   = (const float*)d_in[11];

  float* ws = (float*)d_ws;
  const size_t NB = (size_t)NNODES * HID;  // 6.4e6 elements
  const size_t NBH = NB / 2;               // bf16 buffer in float units
  float* t2 = ws;                                              // fp32 jk output
  unsigned short* xb = (unsigned short*)(ws + NB);             // bf16 x
  unsigned short* tmp = (unsigned short*)(ws + NB + NBH);      // bf16 agg out
  unsigned short* hq[4];
  for (int l = 0; l < 4; ++l)
    hq[l] = (unsigned short*)(ws + NB + (2 + l) * NBH);  // bf16 pre-BN h
  float* ab = ws + NB + 6 * NBH;                         // 4 x {alpha[128], beta[128]}
  float* bjk = ab + 1024;                                // folded jk bias
  int* flag = (int*)(bjk + 128);
  int* deg = flag + 4;
  int* off = deg + (NNODES + 1);
  int* bsum = off + (NNODES + 1);
  int* boff = bsum + 256;
  int* degC = boff + 260;              // NCOPY x NNODES
  int* rank = degC + NCOPY * NNODES;   // NEDGES
  int* srcs = rank + NEDGES;           // NEDGES
  size_t pofs = NB + 6 * NBH + 1024 + 128 + 4 + 2 * (size_t)(NNODES + 1) + 256 + 260 +
                (size_t)NCOPY * NNODES + 2 * (size_t)NEDGES;
  pofs = (pofs + 3) & ~(size_t)3;  // 16B align
  unsigned short* P = (unsigned short*)(ws + pofs);   // W1 at l*16384, W2 at 65536+l*16384
  unsigned short* Pjk = P + 131072;                   // folded lin1 fragments (65536 ushorts)
  // P (131072 us = 65536 fl) + Pjk (65536 us = 32768 fl) = 98304 floats total.
  float* pstats = ws + pofs + 98304;                  // NPBLK x 256 partial stats

  detect64_k<<<1, 256, 0, stream>>>(ei, flag);
  zero_degc_k<<<1563, 256, 0, stream>>>(degC);
  hist_rank_k<<<2344, 256, 0, stream>>>(ei, flag, degC, rank);
  coff_k<<<NBLK, 256, 0, stream>>>(degC, deg);
  blocksum_k<<<NBLK, 256, 0, stream>>>(deg, bsum);
  scanb_k<<<1, 256, 0, stream>>>(bsum, boff);
  writeoff_k<<<NBLK, 256, 0, stream>>>(deg, boff, off);
  fill2_k<<<2344, 256, 0, stream>>>(ei, flag, off, degC, rank, srcs);
  packW_k<<<64, 256, 0, stream>>>(W1, W2, P);
  cvt_bf_k<<<6250, 256, 0, stream>>>(x, xb, NNODES * 32);

  for (int l = 0; l < NLAYERS; ++l) {
    if (l == 0)
      gather_agg_k<false><<<6250, 256, 0, stream>>>(xb, off, srcs, nullptr, tmp);
    else
      gather_agg_k<true><<<6250, 256, 0, stream>>>(hq[l - 1], off, srcs, ab + (l - 1) * 256,
                                                   tmp);
    mlp_k<<<NPBLK, 128, 0, stream>>>(tmp, P + (size_t)l * 16384, b1 + l * HID,
                                     P + 65536 + (size_t)l * 16384, b2 + l * HID, hq[l],
                                     NNODES, pstats);
    reduce_ab_k<<<128, 256, 0, stream>>>(pstats, gamma + l * HID, beta + l * HID,
                                         ab + l * 256);
  }
  packjk_k<<<32, 256, 0, stream>>>(l1W, ab, Pjk);
  biasjk_k<<<1, 128, 0, stream>>>(l1W, ab, l1b, bjk);
  mjkgemm_k<<<NPBLK, 128, 0, stream>>>(hq[0], hq[1], hq[2], hq[3], Pjk, bjk, t2, NNODES);
  head_k<<<196, 256, 0, stream>>>(t2, l2W, l2b, (float*)d_out, NNODES);
}

// Round 16
// 329.414 us; speedup vs baseline: 1.0066x; 1.0066x over previous
//
#include <hip/hip_runtime.h>

#define NNODES 50000
#define NEDGES 600000
#define HID 128
#define NLAYERS 4
#define NOUT 8
#define BN_EPS 1e-5f
#define NBLK 196    // ceil(NNODES/256)
#define NPBLK 3125  // NNODES/16 — 16-row MFMA blocks (2 waves, N-split)
#define NCOPY 8     // histogram copies (XCD-affine via blockIdx%8)
#define IDXCAP 1024 // staged edge-index capacity per gather block
#define RED1 125    // stage-1 reduce blocks (125 x 25 = NPBLK)

typedef short short8 __attribute__((ext_vector_type(8)));
typedef float f32x4 __attribute__((ext_vector_type(4)));

__device__ inline unsigned short f2bf(float f) {
  unsigned u = __float_as_uint(f);
  unsigned r = ((u >> 16) & 1u) + 0x7fffu;
  return (unsigned short)((u + r) >> 16);
}
__device__ inline float bflo(unsigned w) { return __uint_as_float(w << 16); }
__device__ inline float bfhi(unsigned w) { return __uint_as_float(w & 0xffff0000u); }

// ---------------- utility kernels ----------------

// Detect whether edge_index arrived as int64 (odd int32 words all zero) or int32.
__global__ void detect64_k(const int* __restrict__ ei, int* __restrict__ flag) {
  __shared__ int anynz;
  if (threadIdx.x == 0) anynz = 0;
  __syncthreads();
  int acc = 0;
  for (int i = threadIdx.x; i < 4096; i += 256) {
    int p = i * 146;
    acc |= ei[2 * p + 1];
  }
  if (acc != 0) anynz = 1;
  __syncthreads();
  if (threadIdx.x == 0) *flag = (anynz == 0) ? 1 : 0;  // 1 => int64 layout
}

// fp32 -> bf16 convert (for the input x gather table)
__global__ void cvt_bf_k(const float* __restrict__ src, unsigned short* __restrict__ dst,
                         int n4) {
  int i = blockIdx.x * 256 + threadIdx.x;
  if (i >= n4) return;
  float4 v = ((const float4*)src)[i];
  ushort4 o;
  o.x = f2bf(v.x);
  o.y = f2bf(v.y);
  o.z = f2bf(v.z);
  o.w = f2bf(v.w);
  ((ushort4*)dst)[i] = o;
}

// ---------------- CSR build (8-copy histogram, rank capture, no-atomic fill) --------

__global__ void zero_degc_k(int* __restrict__ degC) {
  int i = blockIdx.x * 256 + threadIdx.x;
  if (i < NCOPY * NNODES) degC[i] = 0;
}

__global__ void hist_rank_k(const int* __restrict__ ei, const int* __restrict__ flag,
                            int* __restrict__ degC, int* __restrict__ rank) {
  int e = blockIdx.x * 256 + threadIdx.x;
  if (e >= NEDGES) return;
  int d = (*flag) ? ei[2 * NEDGES + 2 * e] : ei[NEDGES + e];
  int c = blockIdx.x & (NCOPY - 1);
  rank[e] = atomicAdd(&degC[c * NNODES + d], 1);
}

__global__ void coff_k(int* __restrict__ degC, int* __restrict__ deg) {
  int d = blockIdx.x * 256 + threadIdx.x;
  if (d >= NNODES) return;
  int run = 0;
#pragma unroll
  for (int c = 0; c < NCOPY; ++c) {
    int t = degC[c * NNODES + d];
    degC[c * NNODES + d] = run;
    run += t;
  }
  deg[d] = run;
}

__global__ void blocksum_k(const int* __restrict__ deg, int* __restrict__ bsum) {
  int t = threadIdx.x;
  int i = blockIdx.x * 256 + t;
  __shared__ int sh[256];
  sh[t] = (i < NNODES) ? deg[i] : 0;
  __syncthreads();
  for (int s = 128; s > 0; s >>= 1) {
    if (t < s) sh[t] += sh[t + s];
    __syncthreads();
  }
  if (t == 0) bsum[blockIdx.x] = sh[0];
}

__global__ void scanb_k(const int* __restrict__ bsum, int* __restrict__ boff) {
  __shared__ int sh[256];
  int t = threadIdx.x;
  sh[t] = (t < NBLK) ? bsum[t] : 0;
  __syncthreads();
  for (int d = 1; d < 256; d <<= 1) {
    int v = (t >= d) ? sh[t - d] : 0;
    __syncthreads();
    sh[t] += v;
    __syncthreads();
  }
  if (t < NBLK) boff[t] = (t == 0) ? 0 : sh[t - 1];
}

__global__ void writeoff_k(const int* __restrict__ deg, const int* __restrict__ boff,
                           int* __restrict__ off) {
  int t = threadIdx.x;
  int i = blockIdx.x * 256 + t;
  __shared__ int sh[256];
  int v = (i < NNODES) ? deg[i] : 0;
  sh[t] = v;
  __syncthreads();
  for (int d = 1; d < 256; d <<= 1) {
    int u = (t >= d) ? sh[t - d] : 0;
    __syncthreads();
    sh[t] += u;
    __syncthreads();
  }
  int excl = boff[blockIdx.x] + sh[t] - v;
  if (i < NNODES) off[i] = excl;
  if (i == NNODES - 1) off[NNODES] = excl + v;
}

__global__ void fill2_k(const int* __restrict__ ei, const int* __restrict__ flag,
                        const int* __restrict__ off, const int* __restrict__ degC,
                        const int* __restrict__ rank, int* __restrict__ srcs) {
  int e = blockIdx.x * 256 + threadIdx.x;
  if (e >= NEDGES) return;
  int s, d;
  if (*flag) {
    s = ei[2 * e];
    d = ei[2 * NEDGES + 2 * e];
  } else {
    s = ei[e];
    d = ei[NEDGES + e];
  }
  int c = blockIdx.x & (NCOPY - 1);
  srcs[off[d] + degC[c * NNODES + d] + rank[e]] = s;
}

// ---------------- fused gather-aggregate + optional BN affine ----------------
template <bool AFFINE>
__global__ void gather_agg_k(const unsigned short* __restrict__ X,
                             const int* __restrict__ off, const int* __restrict__ srcs,
                             const float* __restrict__ ab, unsigned short* __restrict__ T) {
  __shared__ int sOff[9];
  __shared__ int sIdx[IDXCAP];
  int tid = threadIdx.x;
  int nb = blockIdx.x * 8;
  if (tid < 9) sOff[tid] = off[nb + tid];
  __syncthreads();
  int base = sOff[0];
  int total = sOff[8] - base;
  int stage = total > IDXCAP ? IDXCAP : total;
  for (int t = tid; t < stage; t += 256) sIdx[t] = srcs[base + t];
  __syncthreads();

  int g = tid >> 5, lane = tid & 31;
  int node = nb + g;
  int a = sOff[g] - base, bnd = sOff[g + 1] - base;
  const uint2* Xv = (const uint2*)X;
  uint2 w = Xv[(size_t)node * 32 + lane];
  float a0 = bflo(w.x), a1 = bfhi(w.x), a2 = bflo(w.y), a3 = bfhi(w.y);

  if (total <= IDXCAP) {
    int e = a;
#pragma unroll
    for (; e + 4 <= bnd; e += 4) {
      int s0 = sIdx[e], s1 = sIdx[e + 1], s2 = sIdx[e + 2], s3 = sIdx[e + 3];
      uint2 v0 = Xv[(size_t)s0 * 32 + lane];
      uint2 v1 = Xv[(size_t)s1 * 32 + lane];
      uint2 v2 = Xv[(size_t)s2 * 32 + lane];
      uint2 v3 = Xv[(size_t)s3 * 32 + lane];
      a0 += bflo(v0.x); a1 += bfhi(v0.x); a2 += bflo(v0.y); a3 += bfhi(v0.y);
      a0 += bflo(v1.x); a1 += bfhi(v1.x); a2 += bflo(v1.y); a3 += bfhi(v1.y);
      a0 += bflo(v2.x); a1 += bfhi(v2.x); a2 += bflo(v2.y); a3 += bfhi(v2.y);
      a0 += bflo(v3.x); a1 += bfhi(v3.x); a2 += bflo(v3.y); a3 += bfhi(v3.y);
    }
    for (; e < bnd; ++e) {
      int s = sIdx[e];
      uint2 v = Xv[(size_t)s * 32 + lane];
      a0 += bflo(v.x); a1 += bfhi(v.x); a2 += bflo(v.y); a3 += bfhi(v.y);
    }
  } else {
    for (int e = a; e < bnd; ++e) {
      int s = srcs[base + e];
      uint2 v = Xv[(size_t)s * 32 + lane];
      a0 += bflo(v.x); a1 += bfhi(v.x); a2 += bflo(v.y); a3 += bfhi(v.y);
    }
  }

  if (AFFINE) {
    float4 al = *(const float4*)(ab + lane * 4);
    float4 be = *(const float4*)(ab + 128 + lane * 4);
    float dp1 = (float)(bnd - a + 1);  // 1 + deg (self term)
    a0 = al.x * a0 + dp1 * be.x;
    a1 = al.y * a1 + dp1 * be.y;
    a2 = al.z * a2 + dp1 * be.z;
    a3 = al.w * a3 + dp1 * be.w;
  }

  uint2 o;
  o.x = (unsigned)f2bf(a0) | ((unsigned)f2bf(a1) << 16);
  o.y = (unsigned)f2bf(a2) | ((unsigned)f2bf(a3) << 16);
  ((uint2*)T)[(size_t)node * 32 + lane] = o;
}

// ---------------- weight pre-pack into MFMA B-fragment layout (W1, W2 only) --------
__global__ void packW_k(const float* __restrict__ W1, const float* __restrict__ W2,
                        unsigned short* __restrict__ P) {
  int t = blockIdx.x * 256 + threadIdx.x;
  if (t >= 32 * 512) return;
  int gk = t >> 9;
  int nt = (t >> 6) & 7;
  int lane = t & 63;
  const float* src;
  int kbase;
  if (gk < 16) {
    src = W1 + (gk >> 2) * 16384;
    kbase = (gk & 3) * 32;
  } else {
    src = W2 + ((gk - 16) >> 2) * 16384;
    kbase = ((gk - 16) & 3) * 32;
  }
  int n = nt * 16 + (lane & 15);
  int k0 = kbase + (lane >> 4) * 8;
  unsigned short* dst = P + (size_t)t * 8;
#pragma unroll
  for (int j = 0; j < 8; ++j) dst[j] = f2bf(src[(size_t)(k0 + j) * HID + n]);
}

// ---------------- JK weight pack with alpha fold: W'[K,n] = alpha_K * L1[K,n] --------
__global__ void packjk_k(const float* __restrict__ L1, const float* __restrict__ ab,
                         unsigned short* __restrict__ Pjk) {
  int t = blockIdx.x * 256 + threadIdx.x;
  if (t >= 16 * 512) return;
  int gk = t >> 9;
  int nt = (t >> 6) & 7;
  int lane = t & 63;
  int n = nt * 16 + (lane & 15);
  int k0 = gk * 32 + (lane >> 4) * 8;
  unsigned short* dst = Pjk + (size_t)t * 8;
#pragma unroll
  for (int j = 0; j < 8; ++j) {
    int K = k0 + j;
    float al = ab[(K >> 7) * 256 + (K & 127)];
    dst[j] = f2bf(al * L1[(size_t)K * HID + n]);
  }
}

// ---------------- JK bias with beta fold: b'[n] = l1b[n] + sum_K beta_K * L1[K,n] ----
__global__ void biasjk_k(const float* __restrict__ L1, const float* __restrict__ ab,
                         const float* __restrict__ l1b, float* __restrict__ bjk) {
  int n = threadIdx.x;  // 128
  float acc = l1b[n];
  for (int K = 0; K < 4 * HID; ++K) {
    float be = ab[(K >> 7) * 256 + 128 + (K & 127)];
    acc += be * L1[(size_t)K * HID + n];
  }
  bjk[n] = acc;
}

// ---------------- fused MLP: Hq = bf16(relu(relu(A@W1+b1)@W2+b2)); stats -> pstats ----
__global__ __launch_bounds__(128) void mlp_k(const unsigned short* __restrict__ A,
                                             const unsigned short* __restrict__ P1,
                                             const float* __restrict__ bias1,
                                             const unsigned short* __restrict__ P2,
                                             const float* __restrict__ bias2,
                                             unsigned short* __restrict__ Hq, int M,
                                             float* __restrict__ pstats) {
  __shared__ unsigned short sA[16 * 136];
  int tid = threadIdx.x;
  int lane = tid & 63, w = tid >> 6;
  int rb = blockIdx.x * 16;
  int r = rb + (lane & 15);
  int hi = lane >> 4, c = lane & 15;
  int koff = hi * 8;
  int ntb = w * 4;

  short8 a_[4];
  const unsigned short* Ar = A + (size_t)r * HID + koff;
#pragma unroll
  for (int ks = 0; ks < 4; ++ks) a_[ks] = *(const short8*)(Ar + ks * 32);

  const short8* Bp1 = (const short8*)P1;
  f32x4 acc[4];
#pragma unroll
  for (int nt = 0; nt < 4; ++nt) acc[nt] = (f32x4){0.f, 0.f, 0.f, 0.f};
  short8 bcur[4], bnxt[4];
#pragma unroll
  for (int nt = 0; nt < 4; ++nt) bcur[nt] = Bp1[(ntb + nt) * 64 + lane];
#pragma unroll
  for (int ks = 0; ks < 4; ++ks) {
    if (ks < 3) {
#pragma unroll
      for (int nt = 0; nt < 4; ++nt) bnxt[nt] = Bp1[(ks + 1) * 512 + (ntb + nt) * 64 + lane];
    }
#pragma unroll
    for (int nt = 0; nt < 4; ++nt)
      acc[nt] = __builtin_amdgcn_mfma_f32_16x16x32_bf16(a_[ks], bcur[nt], acc[nt], 0, 0, 0);
    if (ks < 3) {
#pragma unroll
      for (int nt = 0; nt < 4; ++nt) bcur[nt] = bnxt[nt];
    }
  }
#pragma unroll
  for (int nt = 0; nt < 4; ++nt) {
    int col = (ntb + nt) * 16 + c;
    float b = bias1[col];
#pragma unroll
    for (int rr = 0; rr < 4; ++rr) {
      float v = fmaxf(acc[nt][rr] + b, 0.f);
      sA[(hi * 4 + rr) * 136 + col] = f2bf(v);
    }
  }
  __syncthreads();

#pragma unroll
  for (int nt = 0; nt < 4; ++nt) acc[nt] = (f32x4){0.f, 0.f, 0.f, 0.f};
  const short8* Bp2 = (const short8*)P2;
#pragma unroll
  for (int nt = 0; nt < 4; ++nt) bcur[nt] = Bp2[(ntb + nt) * 64 + lane];
#pragma unroll
  for (int ks = 0; ks < 4; ++ks) {
    short8 af = *(const short8*)&sA[c * 136 + ks * 32 + koff];
    if (ks < 3) {
#pragma unroll
      for (int nt = 0; nt < 4; ++nt) bnxt[nt] = Bp2[(ks + 1) * 512 + (ntb + nt) * 64 + lane];
    }
#pragma unroll
    for (int nt = 0; nt < 4; ++nt)
      acc[nt] = __builtin_amdgcn_mfma_f32_16x16x32_bf16(af, bcur[nt], acc[nt], 0, 0, 0);
    if (ks < 3) {
#pragma unroll
      for (int nt = 0; nt < 4; ++nt) bcur[nt] = bnxt[nt];
    }
  }
  // epilogue 2: relu + bf16 write + BN stat partials (stats from fp32 values)
  float* dst = pstats + (size_t)blockIdx.x * 256;
#pragma unroll
  for (int nt = 0; nt < 4; ++nt) {
    int col = (ntb + nt) * 16 + c;
    float b = bias2[col];
    float s = 0.f, q = 0.f;
#pragma unroll
    for (int rr = 0; rr < 4; ++rr) {
      int row = rb + hi * 4 + rr;
      float v = fmaxf(acc[nt][rr] + b, 0.f);
      Hq[(size_t)row * HID + col] = f2bf(v);
      s += v;
      q += v * v;
    }
    s += __shfl_xor(s, 16, 64);
    q += __shfl_xor(q, 16, 64);
    s += __shfl_xor(s, 32, 64);
    q += __shfl_xor(q, 32, 64);
    if (hi == 0) {
      dst[col] = s;
      dst[128 + col] = q;
    }
  }
}

// ---------------- stage-1 stats reduce: part[b][j] = sum of 25 pstats rows (coalesced) --
__global__ void psum_k(const float* __restrict__ pstats, float* __restrict__ part) {
  int t = threadIdx.x;  // 256 = channel-slot
  size_t r0 = (size_t)blockIdx.x * 25;
  float acc = 0.f;
#pragma unroll 5
  for (int r = 0; r < 25; ++r) acc += pstats[(r0 + r) * 256 + t];
  part[(size_t)blockIdx.x * 256 + t] = acc;
}

// ---------------- stage-2: combine partials, emit ab = {alpha[128], beta[128]} --------
__global__ void ab_k(const float* __restrict__ part, const float* __restrict__ gamma,
                     const float* __restrict__ beta, float* __restrict__ ab) {
  __shared__ float tot[256];
  int t = threadIdx.x;
  float acc = 0.f;
  for (int k = 0; k < RED1; ++k) acc += part[(size_t)k * 256 + t];
  tot[t] = acc;
  __syncthreads();
  if (t < 128) {
    const float invN = 1.0f / (float)NNODES;
    float m = tot[t] * invN;
    float var = tot[128 + t] * invN - m * m;
    float al = gamma[t] * rsqrtf(var + BN_EPS);
    ab[t] = al;
    ab[128 + t] = beta[t] - m * al;
  }
}

// ---------------- fused JK GEMM + head: out = (relu(concat(hq)@W'+b')) @ l2W + l2b ----
__global__ __launch_bounds__(128) void mjkhead_k(const unsigned short* __restrict__ H0,
                                                 const unsigned short* __restrict__ H1,
                                                 const unsigned short* __restrict__ H2,
                                                 const unsigned short* __restrict__ H3,
                                                 const unsigned short* __restrict__ P,
                                                 const float* __restrict__ bias,
                                                 const float* __restrict__ l2W,
                                                 const float* __restrict__ l2b,
                                                 float* __restrict__ out, int M) {
  __shared__ float sT[16][136];   // fp32 t2 tile
  __shared__ float sW[HID * NOUT];
  __shared__ float sb[NOUT];
  int tid = threadIdx.x;
  for (int i = tid; i < HID * NOUT; i += 128) sW[i] = l2W[i];
  if (tid < NOUT) sb[tid] = l2b[tid];

  int lane = tid & 63, w = tid >> 6;
  int rb = blockIdx.x * 16;
  int r = rb + (lane & 15);
  int koff = (lane >> 4) * 8;
  int ntb = w * 4;
  f32x4 acc[4];
#pragma unroll
  for (int nt = 0; nt < 4; ++nt) acc[nt] = (f32x4){0.f, 0.f, 0.f, 0.f};
  const unsigned short* Hs[4] = {H0, H1, H2, H3};
  short8 bcur[4], bnxt[4];
  for (int l = 0; l < 4; ++l) {
    const short8* Bp = (const short8*)(P + l * 16384);
    short8 a_[4];
    const unsigned short* Ar = Hs[l] + (size_t)r * HID + koff;
#pragma unroll
    for (int ks = 0; ks < 4; ++ks) a_[ks] = *(const short8*)(Ar + ks * 32);
#pragma unroll
    for (int nt = 0; nt < 4; ++nt) bcur[nt] = Bp[(ntb + nt) * 64 + lane];
#pragma unroll
    for (int ks = 0; ks < 4; ++ks) {
      if (ks < 3) {
#pragma unroll
        for (int nt = 0; nt < 4; ++nt) bnxt[nt] = Bp[(ks + 1) * 512 + (ntb + nt) * 64 + lane];
      }
#pragma unroll
      for (int nt = 0; nt < 4; ++nt)
        acc[nt] = __builtin_amdgcn_mfma_f32_16x16x32_bf16(a_[ks], bcur[nt], acc[nt], 0, 0, 0);
      if (ks < 3) {
#pragma unroll
        for (int nt = 0; nt < 4; ++nt) bcur[nt] = bnxt[nt];
      }
    }
  }
  int hi = lane >> 4, c = lane & 15;
#pragma unroll
  for (int nt = 0; nt < 4; ++nt) {
    int col = (ntb + nt) * 16 + c;
    float b = bias[col];
#pragma unroll
    for (int rr = 0; rr < 4; ++rr) {
      sT[hi * 4 + rr][col] = fmaxf(acc[nt][rr] + b, 0.f);
    }
  }
  __syncthreads();
  // head: 128 threads = 16 rows x 8 cols
  int row = tid >> 3, j = tid & 7;
  float a = sb[j];
  for (int k = 0; k < HID; ++k) a += sT[row][k] * sW[k * NOUT + j];
  out[(size_t)(rb + row) * NOUT + j] = a;
}

// ---------------- launch ----------------

extern "C" void kernel_launch(void* const* d_in, const int* in_sizes, int n_in,
                              void* d_out, int out_size, void* d_ws, size_t ws_size,
                              hipStream_t stream) {
  const float* x     = (const float*)d_in[0];
  const int*   ei    = (const int*)d_in[1];
  const float* W1    = (const float*)d_in[2];
  const float* b1    = (const float*)d_in[3];
  const float* W2    = (const float*)d_in[4];
  const float* b2    = (const float*)d_in[5];
  const float* gamma = (const float*)d_in[6];
  const float* beta  = (const float*)d_in[7];
  const float* l1W   = (const float*)d_in[8];
  const float* l1b   = (const float*)d_in[9];
  const float* l2W   = (const float*)d_in[10];
  const float* l2b   = (const float*)d_in[11];

  float* ws = (float*)d_ws;
  const size_t NB = (size_t)NNODES * HID;  // 6.4e6 elements
  const size_t NBH = NB / 2;               // bf16 buffer in float units
  float* t2 = ws;  // (unused slot kept for layout stability)
  unsigned short* xb = (unsigned short*)(ws + NB);             // bf16 x
  unsigned short* tmp = (unsigned short*)(ws + NB + NBH);      // bf16 agg out
  unsigned short* hq[4];
  for (int l = 0; l < 4; ++l)
    hq[l] = (unsigned short*)(ws + NB + (2 + l) * NBH);  // bf16 pre-BN h
  float* ab = ws + NB + 6 * NBH;                         // 4 x {alpha[128], beta[128]}
  float* bjk = ab + 1024;                                // folded jk bias
  int* flag = (int*)(bjk + 128);
  int* deg = flag + 4;
  int* off = deg + (NNODES + 1);
  int* bsum = off + (NNODES + 1);
  int* boff = bsum + 256;
  int* degC = boff + 260;              // NCOPY x NNODES
  int* rank = degC + NCOPY * NNODES;   // NEDGES
  int* srcs = rank + NEDGES;           // NEDGES
  size_t pofs = NB + 6 * NBH + 1024 + 128 + 4 + 2 * (size_t)(NNODES + 1) + 256 + 260 +
                (size_t)NCOPY * NNODES + 2 * (size_t)NEDGES;
  pofs = (pofs + 3) & ~(size_t)3;  // 16B align
  unsigned short* P = (unsigned short*)(ws + pofs);   // W1 at l*16384, W2 at 65536+l*16384
  unsigned short* Pjk = P + 131072;                   // folded lin1 fragments (65536 ushorts)
  // P (65536 fl) + Pjk (32768 fl) = 98304 floats total.
  float* pstats = ws + pofs + 98304;                  // NPBLK x 256 partial stats
  float* part = pstats + (size_t)NPBLK * 256;         // RED1 x 256 stage-1 partials

  detect64_k<<<1, 256, 0, stream>>>(ei, flag);
  zero_degc_k<<<1563, 256, 0, stream>>>(degC);
  hist_rank_k<<<2344, 256, 0, stream>>>(ei, flag, degC, rank);
  coff_k<<<NBLK, 256, 0, stream>>>(degC, deg);
  blocksum_k<<<NBLK, 256, 0, stream>>>(deg, bsum);
  scanb_k<<<1, 256, 0, stream>>>(bsum, boff);
  writeoff_k<<<NBLK, 256, 0, stream>>>(deg, boff, off);
  fill2_k<<<2344, 256, 0, stream>>>(ei, flag, off, degC, rank, srcs);
  packW_k<<<64, 256, 0, stream>>>(W1, W2, P);
  cvt_bf_k<<<6250, 256, 0, stream>>>(x, xb, NNODES * 32);

  for (int l = 0; l < NLAYERS; ++l) {
    if (l == 0)
      gather_agg_k<false><<<6250, 256, 0, stream>>>(xb, off, srcs, nullptr, tmp);
    else
      gather_agg_k<true><<<6250, 256, 0, stream>>>(hq[l - 1], off, srcs, ab + (l - 1) * 256,
                                                   tmp);
    mlp_k<<<NPBLK, 128, 0, stream>>>(tmp, P + (size_t)l * 16384, b1 + l * HID,
                                     P + 65536 + (size_t)l * 16384, b2 + l * HID, hq[l],
                                     NNODES, pstats);
    psum_k<<<RED1, 256, 0, stream>>>(pstats, part);
    ab_k<<<1, 256, 0, stream>>>(part, gamma + l * HID, beta + l * HID, ab + l * 256);
  }
  packjk_k<<<32, 256, 0, stream>>>(l1W, ab, Pjk);
  biasjk_k<<<1, 128, 0, stream>>>(l1W, ab, l1b, bjk);
  mjkhead_k<<<NPBLK, 128, 0, stream>>>(hq[0], hq[1], hq[2], hq[3], Pjk, bjk, l2W, l2b,
                                       (float*)d_out, NNODES);
  (void)t2;
}

// Round 17
// 305.903 us; speedup vs baseline: 1.0840x; 1.0769x over previous
//
#include <hip/hip_runtime.h>

#define NNODES 50000
#define NEDGES 600000
#define HID 128
#define NLAYERS 4
#define NOUT 8
#define BN_EPS 1e-5f
#define NBLK 196    // ceil(NNODES/256)
#define NPBLK 3125  // NNODES/16 — 16-row MFMA blocks (2 waves, N-split)
#define NCOPY 8     // histogram copies (XCD-affine via blockIdx%8)
#define IDXCAP 1024 // staged edge-index capacity per gather block
#define RED1 125    // stage-1 reduce blocks (125 x 25 = NPBLK)

typedef short short8 __attribute__((ext_vector_type(8)));
typedef float f32x4 __attribute__((ext_vector_type(4)));

__device__ inline unsigned short f2bf(float f) {
  unsigned u = __float_as_uint(f);
  unsigned r = ((u >> 16) & 1u) + 0x7fffu;
  return (unsigned short)((u + r) >> 16);
}
__device__ inline float bflo(unsigned w) { return __uint_as_float(w << 16); }
__device__ inline float bfhi(unsigned w) { return __uint_as_float(w & 0xffff0000u); }

// ---------------- CSR build (8-copy histogram, rank capture, no-atomic fill) --------

// degC zero + (block 0) int64-layout detection.
__global__ void zero_degc_det_k(int* __restrict__ degC, const int* __restrict__ ei,
                                int* __restrict__ flag) {
  int i = blockIdx.x * 256 + threadIdx.x;
  if (i < NCOPY * NNODES) degC[i] = 0;
  if (blockIdx.x == 0) {
    __shared__ int anynz;
    if (threadIdx.x == 0) anynz = 0;
    __syncthreads();
    int acc = 0;
    for (int t = threadIdx.x; t < 4096; t += 256) {
      int p = t * 146;
      acc |= ei[2 * p + 1];
    }
    if (acc != 0) anynz = 1;
    __syncthreads();
    if (threadIdx.x == 0) *flag = (anynz == 0) ? 1 : 0;  // 1 => int64 layout
  }
}

__global__ void hist_rank_k(const int* __restrict__ ei, const int* __restrict__ flag,
                            int* __restrict__ degC, int* __restrict__ rank) {
  int e = blockIdx.x * 256 + threadIdx.x;
  if (e >= NEDGES) return;
  int d = (*flag) ? ei[2 * NEDGES + 2 * e] : ei[NEDGES + e];
  int c = blockIdx.x & (NCOPY - 1);
  rank[e] = atomicAdd(&degC[c * NNODES + d], 1);
}

// coff (per-node copy-prefix + total degree) fused with per-256-chunk blocksum.
__global__ void coff_bsum_k(int* __restrict__ degC, int* __restrict__ deg,
                            int* __restrict__ bsum) {
  int t = threadIdx.x;
  int d = blockIdx.x * 256 + t;
  int run = 0;
  if (d < NNODES) {
#pragma unroll
    for (int c = 0; c < NCOPY; ++c) {
      int v = degC[c * NNODES + d];
      degC[c * NNODES + d] = run;
      run += v;
    }
    deg[d] = run;
  }
  __shared__ int sh[256];
  sh[t] = (d < NNODES) ? run : 0;
  __syncthreads();
  for (int s = 128; s > 0; s >>= 1) {
    if (t < s) sh[t] += sh[t + s];
    __syncthreads();
  }
  if (t == 0) bsum[blockIdx.x] = sh[0];
}

__global__ void scanb_k(const int* __restrict__ bsum, int* __restrict__ boff) {
  __shared__ int sh[256];
  int t = threadIdx.x;
  sh[t] = (t < NBLK) ? bsum[t] : 0;
  __syncthreads();
  for (int d = 1; d < 256; d <<= 1) {
    int v = (t >= d) ? sh[t - d] : 0;
    __syncthreads();
    sh[t] += v;
    __syncthreads();
  }
  if (t < NBLK) boff[t] = (t == 0) ? 0 : sh[t - 1];
}

__global__ void writeoff_k(const int* __restrict__ deg, const int* __restrict__ boff,
                           int* __restrict__ off) {
  int t = threadIdx.x;
  int i = blockIdx.x * 256 + t;
  __shared__ int sh[256];
  int v = (i < NNODES) ? deg[i] : 0;
  sh[t] = v;
  __syncthreads();
  for (int d = 1; d < 256; d <<= 1) {
    int u = (t >= d) ? sh[t - d] : 0;
    __syncthreads();
    sh[t] += u;
    __syncthreads();
  }
  int excl = boff[blockIdx.x] + sh[t] - v;
  if (i < NNODES) off[i] = excl;
  if (i == NNODES - 1) off[NNODES] = excl + v;
}

__global__ void fill2_k(const int* __restrict__ ei, const int* __restrict__ flag,
                        const int* __restrict__ off, const int* __restrict__ degC,
                        const int* __restrict__ rank, int* __restrict__ srcs) {
  int e = blockIdx.x * 256 + threadIdx.x;
  if (e >= NEDGES) return;
  int s, d;
  if (*flag) {
    s = ei[2 * e];
    d = ei[2 * NEDGES + 2 * e];
  } else {
    s = ei[e];
    d = ei[NEDGES + e];
  }
  int c = blockIdx.x & (NCOPY - 1);
  srcs[off[d] + degC[c * NNODES + d] + rank[e]] = s;
}

// ---------------- fused gather-aggregate + optional BN affine ----------------
template <bool AFFINE>
__global__ void gather_agg_k(const unsigned short* __restrict__ X,
                             const int* __restrict__ off, const int* __restrict__ srcs,
                             const float* __restrict__ ab, unsigned short* __restrict__ T) {
  __shared__ int sOff[9];
  __shared__ int sIdx[IDXCAP];
  int tid = threadIdx.x;
  int nb = blockIdx.x * 8;
  if (tid < 9) sOff[tid] = off[nb + tid];
  __syncthreads();
  int base = sOff[0];
  int total = sOff[8] - base;
  int stage = total > IDXCAP ? IDXCAP : total;
  for (int t = tid; t < stage; t += 256) sIdx[t] = srcs[base + t];
  __syncthreads();

  int g = tid >> 5, lane = tid & 31;
  int node = nb + g;
  int a = sOff[g] - base, bnd = sOff[g + 1] - base;
  const uint2* Xv = (const uint2*)X;
  uint2 w = Xv[(size_t)node * 32 + lane];
  float a0 = bflo(w.x), a1 = bfhi(w.x), a2 = bflo(w.y), a3 = bfhi(w.y);

  if (total <= IDXCAP) {
    int e = a;
#pragma unroll
    for (; e + 4 <= bnd; e += 4) {
      int s0 = sIdx[e], s1 = sIdx[e + 1], s2 = sIdx[e + 2], s3 = sIdx[e + 3];
      uint2 v0 = Xv[(size_t)s0 * 32 + lane];
      uint2 v1 = Xv[(size_t)s1 * 32 + lane];
      uint2 v2 = Xv[(size_t)s2 * 32 + lane];
      uint2 v3 = Xv[(size_t)s3 * 32 + lane];
      a0 += bflo(v0.x); a1 += bfhi(v0.x); a2 += bflo(v0.y); a3 += bfhi(v0.y);
      a0 += bflo(v1.x); a1 += bfhi(v1.x); a2 += bflo(v1.y); a3 += bfhi(v1.y);
      a0 += bflo(v2.x); a1 += bfhi(v2.x); a2 += bflo(v2.y); a3 += bfhi(v2.y);
      a0 += bflo(v3.x); a1 += bfhi(v3.x); a2 += bflo(v3.y); a3 += bfhi(v3.y);
    }
    for (; e < bnd; ++e) {
      int s = sIdx[e];
      uint2 v = Xv[(size_t)s * 32 + lane];
      a0 += bflo(v.x); a1 += bfhi(v.x); a2 += bflo(v.y); a3 += bfhi(v.y);
    }
  } else {
    for (int e = a; e < bnd; ++e) {
      int s = srcs[base + e];
      uint2 v = Xv[(size_t)s * 32 + lane];
      a0 += bflo(v.x); a1 += bfhi(v.x); a2 += bflo(v.y); a3 += bfhi(v.y);
    }
  }

  if (AFFINE) {
    float4 al = *(const float4*)(ab + lane * 4);
    float4 be = *(const float4*)(ab + 128 + lane * 4);
    float dp1 = (float)(bnd - a + 1);  // 1 + deg (self term)
    a0 = al.x * a0 + dp1 * be.x;
    a1 = al.y * a1 + dp1 * be.y;
    a2 = al.z * a2 + dp1 * be.z;
    a3 = al.w * a3 + dp1 * be.w;
  }

  uint2 o;
  o.x = (unsigned)f2bf(a0) | ((unsigned)f2bf(a1) << 16);
  o.y = (unsigned)f2bf(a2) | ((unsigned)f2bf(a3) << 16);
  ((uint2*)T)[(size_t)node * 32 + lane] = o;
}

// ---------------- prep: packW (blocks <64) + x->bf16 convert (rest) ----------------
__global__ void prep_k(const float* __restrict__ W1, const float* __restrict__ W2,
                       unsigned short* __restrict__ P, const float* __restrict__ x,
                       unsigned short* __restrict__ xb) {
  if (blockIdx.x < 64) {
    int t = blockIdx.x * 256 + threadIdx.x;  // < 16384 = 32*512
    int gk = t >> 9;
    int nt = (t >> 6) & 7;
    int lane = t & 63;
    const float* src;
    int kbase;
    if (gk < 16) {
      src = W1 + (gk >> 2) * 16384;
      kbase = (gk & 3) * 32;
    } else {
      src = W2 + ((gk - 16) >> 2) * 16384;
      kbase = ((gk - 16) & 3) * 32;
    }
    int n = nt * 16 + (lane & 15);
    int k0 = kbase + (lane >> 4) * 8;
    unsigned short* dst = P + (size_t)t * 8;
#pragma unroll
    for (int j = 0; j < 8; ++j) dst[j] = f2bf(src[(size_t)(k0 + j) * HID + n]);
  } else {
    int i = (blockIdx.x - 64) * 256 + threadIdx.x;
    if (i >= NNODES * 32) return;
    float4 v = ((const float4*)x)[i];
    ushort4 o;
    o.x = f2bf(v.x);
    o.y = f2bf(v.y);
    o.z = f2bf(v.z);
    o.w = f2bf(v.w);
    ((ushort4*)xb)[i] = o;
  }
}

// ---------------- JK pack (blocks <32) + parallel folded bias (blocks 32..159) -------
__global__ void packjk2_k(const float* __restrict__ L1, const float* __restrict__ ab,
                          unsigned short* __restrict__ Pjk, const float* __restrict__ l1b,
                          float* __restrict__ bjk) {
  if (blockIdx.x < 32) {
    int t = blockIdx.x * 256 + threadIdx.x;  // < 8192 = 16*512
    int gk = t >> 9;
    int nt = (t >> 6) & 7;
    int lane = t & 63;
    int n = nt * 16 + (lane & 15);
    int k0 = gk * 32 + (lane >> 4) * 8;
    unsigned short* dst = Pjk + (size_t)t * 8;
#pragma unroll
    for (int j = 0; j < 8; ++j) {
      int K = k0 + j;
      float al = ab[(K >> 7) * 256 + (K & 127)];
      dst[j] = f2bf(al * L1[(size_t)K * HID + n]);
    }
  } else {
    // one block per output column n: bjk[n] = l1b[n] + sum_K beta_K * L1[K,n]
    int n = blockIdx.x - 32;  // 0..127
    int t = threadIdx.x;      // 256
    float acc = 0.f;
#pragma unroll
    for (int h = 0; h < 2; ++h) {
      int K = t + h * 256;
      float be = ab[(K >> 7) * 256 + 128 + (K & 127)];
      acc += be * L1[(size_t)K * HID + n];
    }
    __shared__ float sh[256];
    sh[t] = acc;
    __syncthreads();
    for (int s = 128; s > 0; s >>= 1) {
      if (t < s) sh[t] += sh[t + s];
      __syncthreads();
    }
    if (t == 0) bjk[n] = l1b[n] + sh[0];
  }
}

// ---------------- fused MLP: Hq = bf16(relu(relu(A@W1+b1)@W2+b2)); stats -> pstats ----
__global__ __launch_bounds__(128) void mlp_k(const unsigned short* __restrict__ A,
                                             const unsigned short* __restrict__ P1,
                                             const float* __restrict__ bias1,
                                             const unsigned short* __restrict__ P2,
                                             const float* __restrict__ bias2,
                                             unsigned short* __restrict__ Hq, int M,
                                             float* __restrict__ pstats) {
  __shared__ unsigned short sA[16 * 136];
  int tid = threadIdx.x;
  int lane = tid & 63, w = tid >> 6;
  int rb = blockIdx.x * 16;
  int r = rb + (lane & 15);
  int hi = lane >> 4, c = lane & 15;
  int koff = hi * 8;
  int ntb = w * 4;

  short8 a_[4];
  const unsigned short* Ar = A + (size_t)r * HID + koff;
#pragma unroll
  for (int ks = 0; ks < 4; ++ks) a_[ks] = *(const short8*)(Ar + ks * 32);

  const short8* Bp1 = (const short8*)P1;
  f32x4 acc[4];
#pragma unroll
  for (int nt = 0; nt < 4; ++nt) acc[nt] = (f32x4){0.f, 0.f, 0.f, 0.f};
  short8 bcur[4], bnxt[4];
#pragma unroll
  for (int nt = 0; nt < 4; ++nt) bcur[nt] = Bp1[(ntb + nt) * 64 + lane];
#pragma unroll
  for (int ks = 0; ks < 4; ++ks) {
    if (ks < 3) {
#pragma unroll
      for (int nt = 0; nt < 4; ++nt) bnxt[nt] = Bp1[(ks + 1) * 512 + (ntb + nt) * 64 + lane];
    }
#pragma unroll
    for (int nt = 0; nt < 4; ++nt)
      acc[nt] = __builtin_amdgcn_mfma_f32_16x16x32_bf16(a_[ks], bcur[nt], acc[nt], 0, 0, 0);
    if (ks < 3) {
#pragma unroll
      for (int nt = 0; nt < 4; ++nt) bcur[nt] = bnxt[nt];
    }
  }
#pragma unroll
  for (int nt = 0; nt < 4; ++nt) {
    int col = (ntb + nt) * 16 + c;
    float b = bias1[col];
#pragma unroll
    for (int rr = 0; rr < 4; ++rr) {
      float v = fmaxf(acc[nt][rr] + b, 0.f);
      sA[(hi * 4 + rr) * 136 + col] = f2bf(v);
    }
  }
  __syncthreads();

#pragma unroll
  for (int nt = 0; nt < 4; ++nt) acc[nt] = (f32x4){0.f, 0.f, 0.f, 0.f};
  const short8* Bp2 = (const short8*)P2;
#pragma unroll
  for (int nt = 0; nt < 4; ++nt) bcur[nt] = Bp2[(ntb + nt) * 64 + lane];
#pragma unroll
  for (int ks = 0; ks < 4; ++ks) {
    short8 af = *(const short8*)&sA[c * 136 + ks * 32 + koff];
    if (ks < 3) {
#pragma unroll
      for (int nt = 0; nt < 4; ++nt) bnxt[nt] = Bp2[(ks + 1) * 512 + (ntb + nt) * 64 + lane];
    }
#pragma unroll
    for (int nt = 0; nt < 4; ++nt)
      acc[nt] = __builtin_amdgcn_mfma_f32_16x16x32_bf16(af, bcur[nt], acc[nt], 0, 0, 0);
    if (ks < 3) {
#pragma unroll
      for (int nt = 0; nt < 4; ++nt) bcur[nt] = bnxt[nt];
    }
  }
  // epilogue 2: relu + bf16 write + BN stat partials (stats from fp32 values)
  float* dst = pstats + (size_t)blockIdx.x * 256;
#pragma unroll
  for (int nt = 0; nt < 4; ++nt) {
    int col = (ntb + nt) * 16 + c;
    float b = bias2[col];
    float s = 0.f, q = 0.f;
#pragma unroll
    for (int rr = 0; rr < 4; ++rr) {
      int row = rb + hi * 4 + rr;
      float v = fmaxf(acc[nt][rr] + b, 0.f);
      Hq[(size_t)row * HID + col] = f2bf(v);
      s += v;
      q += v * v;
    }
    s += __shfl_xor(s, 16, 64);
    q += __shfl_xor(q, 16, 64);
    s += __shfl_xor(s, 32, 64);
    q += __shfl_xor(q, 32, 64);
    if (hi == 0) {
      dst[col] = s;
      dst[128 + col] = q;
    }
  }
}

// ---------------- stage-1 stats reduce: part[b][j] = sum of 25 pstats rows (coalesced) --
__global__ void psum_k(const float* __restrict__ pstats, float* __restrict__ part) {
  int t = threadIdx.x;  // 256 = channel-slot
  size_t r0 = (size_t)blockIdx.x * 25;
  float acc = 0.f;
#pragma unroll 5
  for (int r = 0; r < 25; ++r) acc += pstats[(r0 + r) * 256 + t];
  part[(size_t)blockIdx.x * 256 + t] = acc;
}

// ---------------- stage-2: combine partials, emit ab = {alpha[128], beta[128]} --------
__global__ void ab_k(const float* __restrict__ part, const float* __restrict__ gamma,
                     const float* __restrict__ beta, float* __restrict__ ab) {
  __shared__ float tot[256];
  int t = threadIdx.x;
  float acc = 0.f;
  for (int k = 0; k < RED1; ++k) acc += part[(size_t)k * 256 + t];
  tot[t] = acc;
  __syncthreads();
  if (t < 128) {
    const float invN = 1.0f / (float)NNODES;
    float m = tot[t] * invN;
    float var = tot[128 + t] * invN - m * m;
    float al = gamma[t] * rsqrtf(var + BN_EPS);
    ab[t] = al;
    ab[128 + t] = beta[t] - m * al;
  }
}

// ---------------- fused JK GEMM + head: out = (relu(concat(hq)@W'+b')) @ l2W + l2b ----
__global__ __launch_bounds__(128) void mjkhead_k(const unsigned short* __restrict__ H0,
                                                 const unsigned short* __restrict__ H1,
                                                 const unsigned short* __restrict__ H2,
                                                 const unsigned short* __restrict__ H3,
                                                 const unsigned short* __restrict__ P,
                                                 const float* __restrict__ bias,
                                                 const float* __restrict__ l2W,
                                                 const float* __restrict__ l2b,
                                                 float* __restrict__ out, int M) {
  __shared__ float sT[16][136];   // fp32 t2 tile
  __shared__ float sW[HID * NOUT];
  __shared__ float sb[NOUT];
  int tid = threadIdx.x;
  for (int i = tid; i < HID * NOUT; i += 128) sW[i] = l2W[i];
  if (tid < NOUT) sb[tid] = l2b[tid];

  int lane = tid & 63, w = tid >> 6;
  int rb = blockIdx.x * 16;
  int r = rb + (lane & 15);
  int koff = (lane >> 4) * 8;
  int ntb = w * 4;
  f32x4 acc[4];
#pragma unroll
  for (int nt = 0; nt < 4; ++nt) acc[nt] = (f32x4){0.f, 0.f, 0.f, 0.f};
  const unsigned short* Hs[4] = {H0, H1, H2, H3};
  short8 bcur[4], bnxt[4];
  for (int l = 0; l < 4; ++l) {
    const short8* Bp = (const short8*)(P + l * 16384);
    short8 a_[4];
    const unsigned short* Ar = Hs[l] + (size_t)r * HID + koff;
#pragma unroll
    for (int ks = 0; ks < 4; ++ks) a_[ks] = *(const short8*)(Ar + ks * 32);
#pragma unroll
    for (int nt = 0; nt < 4; ++nt) bcur[nt] = Bp[(ntb + nt) * 64 + lane];
#pragma unroll
    for (int ks = 0; ks < 4; ++ks) {
      if (ks < 3) {
#pragma unroll
        for (int nt = 0; nt < 4; ++nt) bnxt[nt] = Bp[(ks + 1) * 512 + (ntb + nt) * 64 + lane];
      }
#pragma unroll
      for (int nt = 0; nt < 4; ++nt)
        acc[nt] = __builtin_amdgcn_mfma_f32_16x16x32_bf16(a_[ks], bcur[nt], acc[nt], 0, 0, 0);
      if (ks < 3) {
#pragma unroll
        for (int nt = 0; nt < 4; ++nt) bcur[nt] = bnxt[nt];
      }
    }
  }
  int hi = lane >> 4, c = lane & 15;
#pragma unroll
  for (int nt = 0; nt < 4; ++nt) {
    int col = (ntb + nt) * 16 + c;
    float b = bias[col];
#pragma unroll
    for (int rr = 0; rr < 4; ++rr) {
      sT[hi * 4 + rr][col] = fmaxf(acc[nt][rr] + b, 0.f);
    }
  }
  __syncthreads();
  // head: 128 threads = 16 rows x 8 cols
  int row = tid >> 3, j = tid & 7;
  float a = sb[j];
  for (int k = 0; k < HID; ++k) a += sT[row][k] * sW[k * NOUT + j];
  out[(size_t)(rb + row) * NOUT + j] = a;
}

// ---------------- launch ----------------

extern "C" void kernel_launch(void* const* d_in, const int* in_sizes, int n_in,
                              void* d_out, int out_size, void* d_ws, size_t ws_size,
                              hipStream_t stream) {
  const float* x     = (const float*)d_in[0];
  const int*   ei    = (const int*)d_in[1];
  const float* W1    = (const float*)d_in[2];
  const float* b1    = (const float*)d_in[3];
  const float* W2    = (const float*)d_in[4];
  const float* b2    = (const float*)d_in[5];
  const float* gamma = (const float*)d_in[6];
  const float* beta  = (const float*)d_in[7];
  const float* l1W   = (const float*)d_in[8];
  const float* l1b   = (const float*)d_in[9];
  const float* l2W   = (const float*)d_in[10];
  const float* l2b   = (const float*)d_in[11];

  float* ws = (float*)d_ws;
  const size_t NB = (size_t)NNODES * HID;  // 6.4e6 elements
  const size_t NBH = NB / 2;               // bf16 buffer in float units
  unsigned short* xb = (unsigned short*)(ws + NB);             // bf16 x
  unsigned short* tmp = (unsigned short*)(ws + NB + NBH);      // bf16 agg out
  unsigned short* hq[4];
  for (int l = 0; l < 4; ++l)
    hq[l] = (unsigned short*)(ws + NB + (2 + l) * NBH);  // bf16 pre-BN h
  float* ab = ws + NB + 6 * NBH;                         // 4 x {alpha[128], beta[128]}
  float* bjk = ab + 1024;                                // folded jk bias
  int* flag = (int*)(bjk + 128);
  int* deg = flag + 4;
  int* off = deg + (NNODES + 1);
  int* bsum = off + (NNODES + 1);
  int* boff = bsum + 256;
  int* degC = boff + 260;              // NCOPY x NNODES
  int* rank = degC + NCOPY * NNODES;   // NEDGES
  int* srcs = rank + NEDGES;           // NEDGES
  size_t pofs = NB + 6 * NBH + 1024 + 128 + 4 + 2 * (size_t)(NNODES + 1) + 256 + 260 +
                (size_t)NCOPY * NNODES + 2 * (size_t)NEDGES;
  pofs = (pofs + 3) & ~(size_t)3;  // 16B align
  unsigned short* P = (unsigned short*)(ws + pofs);   // W1 at l*16384, W2 at 65536+l*16384
  unsigned short* Pjk = P + 131072;                   // folded lin1 fragments (65536 ushorts)
  // P (65536 fl) + Pjk (32768 fl) = 98304 floats total.
  float* pstats = ws + pofs + 98304;                  // NPBLK x 256 partial stats
  float* part = pstats + (size_t)NPBLK * 256;         // RED1 x 256 stage-1 partials

  zero_degc_det_k<<<1563, 256, 0, stream>>>(degC, ei, flag);
  hist_rank_k<<<2344, 256, 0, stream>>>(ei, flag, degC, rank);
  coff_bsum_k<<<NBLK, 256, 0, stream>>>(degC, deg, bsum);
  scanb_k<<<1, 256, 0, stream>>>(bsum, boff);
  writeoff_k<<<NBLK, 256, 0, stream>>>(deg, boff, off);
  fill2_k<<<2344, 256, 0, stream>>>(ei, flag, off, degC, rank, srcs);
  prep_k<<<6314, 256, 0, stream>>>(W1, W2, P, x, xb);

  for (int l = 0; l < NLAYERS; ++l) {
    if (l == 0)
      gather_agg_k<false><<<6250, 256, 0, stream>>>(xb, off, srcs, nullptr, tmp);
    else
      gather_agg_k<true><<<6250, 256, 0, stream>>>(hq[l - 1], off, srcs, ab + (l - 1) * 256,
                                                   tmp);
    mlp_k<<<NPBLK, 128, 0, stream>>>(tmp, P + (size_t)l * 16384, b1 + l * HID,
                                     P + 65536 + (size_t)l * 16384, b2 + l * HID, hq[l],
                                     NNODES, pstats);
    psum_k<<<RED1, 256, 0, stream>>>(pstats, part);
    ab_k<<<1, 256, 0, stream>>>(part, gamma + l * HID, beta + l * HID, ab + l * 256);
  }
  packjk2_k<<<160, 256, 0, stream>>>(l1W, ab, Pjk, l1b, bjk);
  mjkhead_k<<<NPBLK, 128, 0, stream>>>(hq[0], hq[1], hq[2], hq[3], Pjk, bjk, l2W, l2b,
                                       (float*)d_out, NNODES);
}